// Round 9
// baseline (308.437 us; speedup 1.0000x reference)
//
#include <hip/hip_runtime.h>
#include <hip/hip_bf16.h>
#include <math.h>

#define NEG_SLOPE 0.2f
// wave-internal LDS ordering: each wave owns a private LDS slice, so a plain
// lgkmcnt drain orders its own ds ops; no __syncthreads (degrees diverge).
#define LDS_FENCE() asm volatile("s_waitcnt lgkmcnt(0)" ::: "memory")

// ===================== partition-sort CSR build (dst-indexed) =====================
// Partitions of 32 dst values; NP = ceil(N/32) <= 384; NB = 128 scatter blocks.
// hist layout TRANSPOSED: hist[p*CSR_NB + b] so the scan pass is parallel
// (r8's k_partscan was a serial 128-step global-latency chain per thread).
#define CSR_NB 128

// pass A: per-block histogram over partitions
__global__ __launch_bounds__(256) void k_parthist(const int* __restrict__ ei, int E, int N,
                                                  int NP, int CE, int* __restrict__ hist) {
    __shared__ int lhist[384];
    int t = threadIdx.x, b = blockIdx.x;
    for (int p = t; p < 384; p += 256) lhist[p] = 0;
    __syncthreads();
    int Etot = E + N;
    int e0 = b * CE, e1 = min(Etot, e0 + CE);
    for (int e = e0 + t; e < e1; e += 256) {
        int d = (e < E) ? ei[E + e] : (e - E);
        atomicAdd(&lhist[d >> 5], 1);
    }
    __syncthreads();
    for (int p = t; p < NP; p += 256) hist[p * CSR_NB + b] = lhist[p];
}

// pass R: per-partition scan over the 128 block-counts (parallel, 313 blocks)
__global__ __launch_bounds__(128) void k_partreduce(int* __restrict__ hist,
                                                    int* __restrict__ partTot) {
    __shared__ int w0tot;
    int p = blockIdx.x, t = threadIdx.x, lane = t & 63, wv = t >> 6;
    int v = hist[p * CSR_NB + t];
    int x = v;
#pragma unroll
    for (int off = 1; off < 64; off <<= 1) {
        int u = __shfl_up(x, off);
        if (lane >= off) x += u;
    }
    if (wv == 0 && lane == 63) w0tot = x;
    __syncthreads();
    int excl = x - v + (wv ? w0tot : 0);
    hist[p * CSR_NB + t] = excl;
    if (t == 127) partTot[p] = excl + v;
}

// pass S: scan partition totals -> partBase (single small block)
__global__ __launch_bounds__(512) void k_partbase(const int* __restrict__ partTot, int NP,
                                                  int* __restrict__ partBase,
                                                  int* __restrict__ rowptr, int N) {
    __shared__ int wsums[8];
    int t = threadIdx.x, lane = t & 63, wave = t >> 6;
    int v = (t < NP) ? partTot[t] : 0;
    int x = v;
#pragma unroll
    for (int off = 1; off < 64; off <<= 1) {
        int u = __shfl_up(x, off);
        if (lane >= off) x += u;
    }
    if (lane == 63) wsums[wave] = x;
    __syncthreads();
    int wp = 0;
    for (int w = 0; w < 8; ++w)
        if (w < wave) wp += wsums[w];
    int excl = wp + x - v;
    if (t < NP) partBase[t] = excl;
    if (t == NP - 1) {
        partBase[NP] = excl + v;
        rowptr[N] = excl + v;
    }
}

// pass B: scatter packed (src<<5 | dst&31) into partition segments
__global__ __launch_bounds__(256) void k_partscatter(const int* __restrict__ ei, int E, int N,
                                                     int NP, int CE,
                                                     const int* __restrict__ hist,
                                                     const int* __restrict__ partBase,
                                                     int* __restrict__ tmp) {
    __shared__ int cursor[384];
    int t = threadIdx.x, b = blockIdx.x;
    for (int p = t; p < NP; p += 256) cursor[p] = partBase[p] + hist[p * CSR_NB + b];
    __syncthreads();
    int Etot = E + N;
    int e0 = b * CE, e1 = min(Etot, e0 + CE);
    for (int e = e0 + t; e < e1; e += 256) {
        int s, d;
        if (e < E) { s = ei[e]; d = ei[E + e]; } else { s = d = e - E; }
        int pos = atomicAdd(&cursor[d >> 5], 1);   // LDS atomic: fast
        tmp[pos] = (s << 5) | (d & 31);
    }
}

// pass C: one block per partition -> rowptr (dense) + col (dense)
__global__ __launch_bounds__(256) void k_csr_final(const int* __restrict__ tmp,
                                                   const int* __restrict__ partBase,
                                                   int* __restrict__ rowptr,
                                                   int* __restrict__ col, int N) {
    __shared__ int dcnt[32], dcur[32];
    int t = threadIdx.x, p = blockIdx.x;
    int base = partBase[p], end = partBase[p + 1];
    if (t < 32) dcnt[t] = 0;
    __syncthreads();
    for (int i = base + t; i < end; i += 256) atomicAdd(&dcnt[tmp[i] & 31], 1);
    __syncthreads();
    if (t < 32) {
        int v = dcnt[t];
        int x = v;
#pragma unroll
        for (int off = 1; off < 32; off <<= 1) {
            int u = __shfl_up(x, off);
            if (t >= off) x += u;
        }
        int excl = x - v;
        dcur[t] = excl;
        int dst = (p << 5) + t;
        if (dst < N) rowptr[dst] = base + excl;
    }
    __syncthreads();
    for (int i = base + t; i < end; i += 256) {
        int v = tmp[i];
        int pos = atomicAdd(&dcur[v & 31], 1);
        col[base + pos] = v >> 5;
    }
}

// ---------- GEMM: C[n,j] = sum_k X[n,k]*W[k,j], 256 cols total ----------
template <int K>
__global__ __launch_bounds__(256) void k_gemm_cs(const float* __restrict__ X,
                                                 const float* __restrict__ W,
                                                 float* __restrict__ C, int N) {
    __shared__ float xs[32][K];
    int t = threadIdx.x;
    int n0 = blockIdx.x * 32;
    int ch = blockIdx.y;
    for (int idx = t; idx < 32 * (K / 4); idx += 256) {
        int r = idx / (K / 4), kq = idx - r * (K / 4);
        int n = n0 + r;
        float4 v = {0.f, 0.f, 0.f, 0.f};
        if (n < N) v = ((const float4*)(X + (size_t)n * K))[kq];
        *(float4*)&xs[r][kq * 4] = v;
    }
    __syncthreads();
    int lane = t & 63, wave = t >> 6;
    int r0 = wave * 8;
    const float* Wp = W + ch * 128 + lane * 2;
    float2 acc[8] = {};
#pragma unroll 2
    for (int k = 0; k < K; k += 4) {
        float2 w0 = *(const float2*)(Wp + (size_t)k * 256);
        float2 w1 = *(const float2*)(Wp + (size_t)(k + 1) * 256);
        float2 w2 = *(const float2*)(Wp + (size_t)(k + 2) * 256);
        float2 w3 = *(const float2*)(Wp + (size_t)(k + 3) * 256);
#pragma unroll
        for (int rr = 0; rr < 8; ++rr) {
            float4 xv = *(const float4*)&xs[r0 + rr][k];
            acc[rr].x = fmaf(xv.x, w0.x, acc[rr].x);
            acc[rr].y = fmaf(xv.x, w0.y, acc[rr].y);
            acc[rr].x = fmaf(xv.y, w1.x, acc[rr].x);
            acc[rr].y = fmaf(xv.y, w1.y, acc[rr].y);
            acc[rr].x = fmaf(xv.z, w2.x, acc[rr].x);
            acc[rr].y = fmaf(xv.z, w2.y, acc[rr].y);
            acc[rr].x = fmaf(xv.w, w3.x, acc[rr].x);
            acc[rr].y = fmaf(xv.w, w3.y, acc[rr].y);
        }
    }
#pragma unroll
    for (int rr = 0; rr < 8; ++rr) {
        int n = n0 + r0 + rr;
        if (n < N) *(float2*)(C + (size_t)n * 256 + ch * 128 + lane * 2) = acc[rr];
    }
}

// ---------- layer-1 attention logits: thread per (n,h), ch=16 ----------
__global__ void k_logits1(const float* __restrict__ H, const float* __restrict__ a_src,
                          const float* __restrict__ a_dst, float* __restrict__ als,
                          float* __restrict__ ald, int NH) {
    int i = blockIdx.x * blockDim.x + threadIdx.x;
    if (i >= NH) return;
    int h = i & 15;
    const float4* hp = (const float4*)(H + (size_t)i * 16);
    const float4* as = (const float4*)(a_src + h * 16);
    const float4* ad = (const float4*)(a_dst + h * 16);
    float s = 0.f, d = 0.f;
#pragma unroll
    for (int q = 0; q < 4; ++q) {
        float4 hv = hp[q], sv = as[q], dv = ad[q];
        s += hv.x * sv.x + hv.y * sv.y + hv.z * sv.z + hv.w * sv.w;
        d += hv.x * dv.x + hv.y * dv.y + hv.z * dv.z + hv.w * dv.w;
    }
    als[i] = s;
    ald[i] = d;
}

// ---------- layer-2 attention logits: wave per node, D=256 ----------
__global__ __launch_bounds__(256) void k_logits2(const float* __restrict__ H,
                                                 const float* __restrict__ a_src,
                                                 const float* __restrict__ a_dst,
                                                 float* __restrict__ als,
                                                 float* __restrict__ ald, int N) {
    int wave = threadIdx.x >> 6, lane = threadIdx.x & 63;
    int n = blockIdx.x * 4 + wave;
    if (n >= N) return;
    float4 hv = *(const float4*)(H + (size_t)n * 256 + lane * 4);
    float4 sv = *(const float4*)(a_src + lane * 4);
    float4 dv = *(const float4*)(a_dst + lane * 4);
    float s = hv.x * sv.x + hv.y * sv.y + hv.z * sv.z + hv.w * sv.w;
    float d = hv.x * dv.x + hv.y * dv.y + hv.z * dv.z + hv.w * dv.w;
#pragma unroll
    for (int off = 32; off >= 1; off >>= 1) {
        s += __shfl_xor(s, off);
        d += __shfl_xor(d, off);
    }
    if (lane == 0) { als[n] = s; ald[n] = d; }
}

// ---------- XCD-pinned GAT gather, 1 head ----------
// grid.x = 8 * ceil(N/4); cg = blockIdx.x & 7 (round-robin -> XCD cg), so each
// XCD touches only H[:, cg*32 .. cg*32+31] = 1.25MB -> L2-resident; H fetched
// from HBM once total instead of once per XCD (the r3-r8 80MB floor).
// Wave per node; half-wave per edge (2 edges in flight), 4B/lane coalesced.
__global__ __launch_bounds__(256) void k_gather_h1(
    const int* __restrict__ rowptr, const int* __restrict__ col,
    const float* __restrict__ H, const float* __restrict__ als,
    const float* __restrict__ ald, const float* __restrict__ bias,
    float* __restrict__ out, int N) {
    __shared__ float2 sw[4][64];
    int wave = threadIdx.x >> 6, lane = threadIdx.x & 63;
    int b = blockIdx.x;
    int cg = b & 7;
    int n = (b >> 3) * 4 + wave;
    if (n >= N) return;
    int c31 = lane & 31;
    int ep = lane >> 5;               // edge parity this lane accumulates
    int start = rowptr[n], end = rowptr[n + 1];
    float aldv = ald[n];
    float acc = 0.f, swsum = 0.f;
    const float* Hc = H + cg * 32 + c31;
    for (int base = start; base < end; base += 64) {
        int len = min(64, end - base);
        int s = 0;
        float w = 0.f;
        if (lane < len) {
            s = col[base + lane];
            float v = als[s] + aldv;
            v = v >= 0.f ? v : NEG_SLOPE * v;
            w = __expf(v);
        }
        swsum += w;
        sw[wave][lane] = make_float2(__int_as_float(s), w);
        LDS_FENCE();
        for (int e = 0; e < len; e += 2) {
            int eb = e + ep;
            if (eb < len) {
                float2 p = sw[wave][eb];
                acc = fmaf(p.y, Hc[(size_t)__float_as_int(p.x) * 256], acc);
            }
        }
        LDS_FENCE();
    }
#pragma unroll
    for (int off = 32; off >= 1; off >>= 1) swsum += __shfl_xor(swsum, off);
    float inv = 1.0f / swsum;
    acc += __shfl_xor(acc, 32);       // combine even/odd edge partials
    if (lane < 32) {
        int ch = cg * 32 + c31;
        out[(size_t)n * 256 + ch] = fmaf(acc, inv, bias[ch]);
    }
}

// ---------- XCD-pinned GAT gather, 16 heads x 16ch ----------
// cg covers channels cg*32..+31 = heads cg*2, cg*2+1. Staging: 32-edge chunk,
// lane computes w for (edge = lane&31, head = cg*2 + lane/32). Accum: half-wave
// per edge, lane's channel head = cg*2 + (c31>>4).
__global__ __launch_bounds__(256) void k_gather_h16(
    const int* __restrict__ rowptr, const int* __restrict__ col,
    const float* __restrict__ H, const float* __restrict__ als,
    const float* __restrict__ ald, const float* __restrict__ bias,
    float* __restrict__ out, int N) {
    __shared__ int s_lds[4][32];
    __shared__ float w_lds[4][64];    // [edge*2 + hl]
    int wave = threadIdx.x >> 6, lane = threadIdx.x & 63;
    int b = blockIdx.x;
    int cg = b & 7;
    int n = (b >> 3) * 4 + wave;
    if (n >= N) return;
    int c31 = lane & 31;
    int ep = lane >> 5;               // edge parity for accumulation
    int hl = c31 >> 4;                // local head of this lane's channel
    int hS = (cg << 1) + ep;          // head this lane computes logits for
    int start = rowptr[n], end = rowptr[n + 1];
    float aldv = ald[n * 16 + hS];
    float acc = 0.f, swp = 0.f;
    const float* Hc = H + cg * 32 + c31;
    for (int base = start; base < end; base += 32) {
        int len = min(32, end - base);
        if (lane < 32) s_lds[wave][lane] = (lane < len) ? col[base + lane] : 0;
        LDS_FENCE();
        int eS = lane & 31;
        float w = 0.f;
        if (eS < len) {
            int s = s_lds[wave][eS];
            float v = als[s * 16 + hS] + aldv;
            v = v >= 0.f ? v : NEG_SLOPE * v;
            w = __expf(v);
        }
        w_lds[wave][eS * 2 + ep] = w;
        swp += w;
        LDS_FENCE();
        for (int e = 0; e < len; e += 2) {
            int eb = e + ep;
            if (eb < len) {
                int s = s_lds[wave][eb];
                float wv = w_lds[wave][eb * 2 + hl];
                acc = fmaf(wv, Hc[(size_t)s * 256], acc);
            }
        }
        LDS_FENCE();
    }
    // swp: lanes 0..31 hold partials for head cg*2, lanes 32..63 for cg*2+1
#pragma unroll
    for (int off = 1; off < 32; off <<= 1) swp += __shfl_xor(swp, off);
    float s0 = __shfl(swp, 0), s1 = __shfl(swp, 32);
    float inv = 1.0f / (hl ? s1 : s0);
    acc += __shfl_xor(acc, 32);       // combine even/odd edge partials
    if (lane < 32) {
        int ch = cg * 32 + c31;
        out[(size_t)n * 256 + ch] = fmaxf(fmaf(acc, inv, bias[ch]), 0.f);
    }
}

// ---------- fused mean-pool + final linear: one block per graph ----------
__device__ __forceinline__ int lower_bound_i(const int* __restrict__ a, int n, int v) {
    int lo = 0, hi = n;
    while (lo < hi) {
        int mid = (lo + hi) >> 1;
        if (a[mid] < v) lo = mid + 1; else hi = mid;
    }
    return lo;
}

__global__ __launch_bounds__(1024) void k_pool_final(const float* __restrict__ B,
                                                     const int* __restrict__ batch,
                                                     const float* __restrict__ lw,
                                                     const float* __restrict__ lb,
                                                     float* __restrict__ out,
                                                     int N, int L) {
    __shared__ float psum[4][256];
    __shared__ float csum[256];
    int t = threadIdx.x;
    int c = t & 255, q = t >> 8;
    int g = blockIdx.x;
    int lo = lower_bound_i(batch, N, g);
    int hi = lower_bound_i(batch, N, g + 1);
    int len = hi - lo;
    int per = (len + 3) >> 2;
    int s0 = lo + q * per, s1 = min(hi, s0 + per);
    float acc = 0.f;
    for (int r = s0; r < s1; ++r) acc += B[(size_t)r * 256 + c];
    psum[q][c] = acc;
    __syncthreads();
    if (t < 256) csum[t] = psum[0][t] + psum[1][t] + psum[2][t] + psum[3][t];
    __syncthreads();
    int wave = t >> 6, lane = t & 63;
    if (wave < L) {
        int l = wave;
        float a = csum[lane] * lw[lane * L + l] +
                  csum[lane + 64] * lw[(lane + 64) * L + l] +
                  csum[lane + 128] * lw[(lane + 128) * L + l] +
                  csum[lane + 192] * lw[(lane + 192) * L + l];
#pragma unroll
        for (int off = 32; off >= 1; off >>= 1) a += __shfl_xor(a, off);
        if (lane == 0) out[g * L + l] = a / fmaxf((float)len, 1.0f) + lb[l];
    }
}

extern "C" void kernel_launch(void* const* d_in, const int* in_sizes, int n_in,
                              void* d_out, int out_size, void* d_ws, size_t ws_size,
                              hipStream_t stream) {
    const float* x   = (const float*)d_in[0];
    const int*   ei  = (const int*)d_in[1];
    const int*   bat = (const int*)d_in[2];
    const float* W1  = (const float*)d_in[3];
    const float* as1 = (const float*)d_in[4];
    const float* ad1 = (const float*)d_in[5];
    const float* b1  = (const float*)d_in[6];
    const float* W2  = (const float*)d_in[7];
    const float* as2 = (const float*)d_in[8];
    const float* ad2 = (const float*)d_in[9];
    const float* b2  = (const float*)d_in[10];
    const float* lw  = (const float*)d_in[11];
    const float* lb  = (const float*)d_in[12];
    float* out = (float*)d_out;

    const int N = in_sizes[2];        // 10000
    const int E = in_sizes[1] / 2;    // 320000
    const int G = 64, L = 10;
    const int Etot = E + N;
    const int NP = (N + 31) >> 5;     // partitions of 32 dsts (313)
    const int CE = (Etot + CSR_NB - 1) / CSR_NB;

    // workspace layout
    float* A    = (float*)d_ws;              // [N,256] h1 then h2
    float* B    = A + (size_t)N * 256;       // [N,256] out1 then out2
    float* als1 = B + (size_t)N * 256;       // [N,16]
    float* ald1 = als1 + (size_t)N * 16;
    float* als2 = ald1 + (size_t)N * 16;     // [N]
    float* ald2 = als2 + N;
    int* rowptr   = (int*)(ald2 + N);        // [N+1]
    int* col      = rowptr + N + 1;          // [Etot]
    int* tmp      = col + Etot;              // [Etot] packed (src<<5)|d5
    int* hist     = tmp + Etot;              // [NP*CSR_NB] transposed
    int* partBase = hist + NP * CSR_NB;      // [NP+1]
    int* partTot  = partBase + NP + 1;       // [NP]

    const int BS = 256;
    auto nb = [](int n, int b) { return (n + b - 1) / b; };
    int nodes4 = nb(N, 4);
    int rows32 = nb(N, 32);

    // ---- CSR build: partition sort, parallel scan, no global returning atomics ----
    k_parthist<<<CSR_NB, BS, 0, stream>>>(ei, E, N, NP, CE, hist);
    k_partreduce<<<NP, 128, 0, stream>>>(hist, partTot);
    k_partbase<<<1, 512, 0, stream>>>(partTot, NP, partBase, rowptr, N);
    k_partscatter<<<CSR_NB, BS, 0, stream>>>(ei, E, N, NP, CE, hist, partBase, tmp);
    k_csr_final<<<NP, BS, 0, stream>>>(tmp, partBase, rowptr, col, N);

    // ---- layer 1 ----
    k_gemm_cs<128><<<dim3(rows32, 2), BS, 0, stream>>>(x, W1, A, N);
    k_logits1<<<nb(N * 16, BS), BS, 0, stream>>>(A, as1, ad1, als1, ald1, N * 16);
    k_gather_h16<<<8 * nodes4, BS, 0, stream>>>(rowptr, col, A, als1, ald1, b1, B, N);

    // ---- layer 2 ----
    k_gemm_cs<256><<<dim3(rows32, 2), BS, 0, stream>>>(B, W2, A, N);
    k_logits2<<<nodes4, BS, 0, stream>>>(A, as2, ad2, als2, ald2, N);
    k_gather_h1<<<8 * nodes4, BS, 0, stream>>>(rowptr, col, A, als2, ald2, b2, B, N);

    // ---- fused pool + final linear ----
    k_pool_final<<<G, 1024, 0, stream>>>(B, bat, lw, lb, out, N, L);
}

// Round 10
// 261.119 us; speedup vs baseline: 1.1812x; 1.1812x over previous
//
#include <hip/hip_runtime.h>
#include <hip/hip_bf16.h>
#include <math.h>

#define NEG_SLOPE 0.2f
// wave-internal LDS ordering: each wave owns a private LDS slice, so a plain
// lgkmcnt drain orders its own ds ops; no __syncthreads (degrees diverge).
#define LDS_FENCE() asm volatile("s_waitcnt lgkmcnt(0)" ::: "memory")

// ===================== partition-sort CSR build (dst-indexed) =====================
// Partitions of 32 dst values; NP = ceil(N/32) <= 384; NB = 128 scatter blocks.
// hist layout TRANSPOSED: hist[p*CSR_NB + b] so the scan pass is parallel.
#define CSR_NB 128

// pass A: per-block histogram over partitions
__global__ __launch_bounds__(256) void k_parthist(const int* __restrict__ ei, int E, int N,
                                                  int NP, int CE, int* __restrict__ hist) {
    __shared__ int lhist[384];
    int t = threadIdx.x, b = blockIdx.x;
    for (int p = t; p < 384; p += 256) lhist[p] = 0;
    __syncthreads();
    int Etot = E + N;
    int e0 = b * CE, e1 = min(Etot, e0 + CE);
    for (int e = e0 + t; e < e1; e += 256) {
        int d = (e < E) ? ei[E + e] : (e - E);
        atomicAdd(&lhist[d >> 5], 1);
    }
    __syncthreads();
    for (int p = t; p < NP; p += 256) hist[p * CSR_NB + b] = lhist[p];
}

// pass R: per-partition scan over the 128 block-counts (parallel, NP blocks)
__global__ __launch_bounds__(128) void k_partreduce(int* __restrict__ hist,
                                                    int* __restrict__ partTot) {
    __shared__ int w0tot;
    int p = blockIdx.x, t = threadIdx.x, lane = t & 63, wv = t >> 6;
    int v = hist[p * CSR_NB + t];
    int x = v;
#pragma unroll
    for (int off = 1; off < 64; off <<= 1) {
        int u = __shfl_up(x, off);
        if (lane >= off) x += u;
    }
    if (wv == 0 && lane == 63) w0tot = x;
    __syncthreads();
    int excl = x - v + (wv ? w0tot : 0);
    hist[p * CSR_NB + t] = excl;
    if (t == 127) partTot[p] = excl + v;
}

// pass S: scan partition totals -> partBase (single small block)
__global__ __launch_bounds__(512) void k_partbase(const int* __restrict__ partTot, int NP,
                                                  int* __restrict__ partBase,
                                                  int* __restrict__ rowptr, int N) {
    __shared__ int wsums[8];
    int t = threadIdx.x, lane = t & 63, wave = t >> 6;
    int v = (t < NP) ? partTot[t] : 0;
    int x = v;
#pragma unroll
    for (int off = 1; off < 64; off <<= 1) {
        int u = __shfl_up(x, off);
        if (lane >= off) x += u;
    }
    if (lane == 63) wsums[wave] = x;
    __syncthreads();
    int wp = 0;
    for (int w = 0; w < 8; ++w)
        if (w < wave) wp += wsums[w];
    int excl = wp + x - v;
    if (t < NP) partBase[t] = excl;
    if (t == NP - 1) {
        partBase[NP] = excl + v;
        rowptr[N] = excl + v;
    }
}

// pass B: scatter packed (src<<5 | dst&31) into partition segments
__global__ __launch_bounds__(256) void k_partscatter(const int* __restrict__ ei, int E, int N,
                                                     int NP, int CE,
                                                     const int* __restrict__ hist,
                                                     const int* __restrict__ partBase,
                                                     int* __restrict__ tmp) {
    __shared__ int cursor[384];
    int t = threadIdx.x, b = blockIdx.x;
    for (int p = t; p < NP; p += 256) cursor[p] = partBase[p] + hist[p * CSR_NB + b];
    __syncthreads();
    int Etot = E + N;
    int e0 = b * CE, e1 = min(Etot, e0 + CE);
    for (int e = e0 + t; e < e1; e += 256) {
        int s, d;
        if (e < E) { s = ei[e]; d = ei[E + e]; } else { s = d = e - E; }
        int pos = atomicAdd(&cursor[d >> 5], 1);   // LDS atomic: fast
        tmp[pos] = (s << 5) | (d & 31);
    }
}

// pass C: one block per partition -> rowptr (dense) + col (dense)
__global__ __launch_bounds__(256) void k_csr_final(const int* __restrict__ tmp,
                                                   const int* __restrict__ partBase,
                                                   int* __restrict__ rowptr,
                                                   int* __restrict__ col, int N) {
    __shared__ int dcnt[32], dcur[32];
    int t = threadIdx.x, p = blockIdx.x;
    int base = partBase[p], end = partBase[p + 1];
    if (t < 32) dcnt[t] = 0;
    __syncthreads();
    for (int i = base + t; i < end; i += 256) atomicAdd(&dcnt[tmp[i] & 31], 1);
    __syncthreads();
    if (t < 32) {
        int v = dcnt[t];
        int x = v;
#pragma unroll
        for (int off = 1; off < 32; off <<= 1) {
            int u = __shfl_up(x, off);
            if (t >= off) x += u;
        }
        int excl = x - v;
        dcur[t] = excl;
        int dst = (p << 5) + t;
        if (dst < N) rowptr[dst] = base + excl;
    }
    __syncthreads();
    for (int i = base + t; i < end; i += 256) {
        int v = tmp[i];
        int pos = atomicAdd(&dcur[v & 31], 1);
        col[base + pos] = v >> 5;
    }
}

// ---------- GEMM: C[n,j] = sum_k X[n,k]*W[k,j], 256 cols total ----------
template <int K>
__global__ __launch_bounds__(256) void k_gemm_cs(const float* __restrict__ X,
                                                 const float* __restrict__ W,
                                                 float* __restrict__ C, int N) {
    __shared__ float xs[32][K];
    int t = threadIdx.x;
    int n0 = blockIdx.x * 32;
    int ch = blockIdx.y;
    for (int idx = t; idx < 32 * (K / 4); idx += 256) {
        int r = idx / (K / 4), kq = idx - r * (K / 4);
        int n = n0 + r;
        float4 v = {0.f, 0.f, 0.f, 0.f};
        if (n < N) v = ((const float4*)(X + (size_t)n * K))[kq];
        *(float4*)&xs[r][kq * 4] = v;
    }
    __syncthreads();
    int lane = t & 63, wave = t >> 6;
    int r0 = wave * 8;
    const float* Wp = W + ch * 128 + lane * 2;
    float2 acc[8] = {};
#pragma unroll 2
    for (int k = 0; k < K; k += 4) {
        float2 w0 = *(const float2*)(Wp + (size_t)k * 256);
        float2 w1 = *(const float2*)(Wp + (size_t)(k + 1) * 256);
        float2 w2 = *(const float2*)(Wp + (size_t)(k + 2) * 256);
        float2 w3 = *(const float2*)(Wp + (size_t)(k + 3) * 256);
#pragma unroll
        for (int rr = 0; rr < 8; ++rr) {
            float4 xv = *(const float4*)&xs[r0 + rr][k];
            acc[rr].x = fmaf(xv.x, w0.x, acc[rr].x);
            acc[rr].y = fmaf(xv.x, w0.y, acc[rr].y);
            acc[rr].x = fmaf(xv.y, w1.x, acc[rr].x);
            acc[rr].y = fmaf(xv.y, w1.y, acc[rr].y);
            acc[rr].x = fmaf(xv.z, w2.x, acc[rr].x);
            acc[rr].y = fmaf(xv.z, w2.y, acc[rr].y);
            acc[rr].x = fmaf(xv.w, w3.x, acc[rr].x);
            acc[rr].y = fmaf(xv.w, w3.y, acc[rr].y);
        }
    }
#pragma unroll
    for (int rr = 0; rr < 8; ++rr) {
        int n = n0 + r0 + rr;
        if (n < N) *(float2*)(C + (size_t)n * 256 + ch * 128 + lane * 2) = acc[rr];
    }
}

// ---------- layer-1 attention logits: thread per (n,h), ch=16 ----------
__global__ void k_logits1(const float* __restrict__ H, const float* __restrict__ a_src,
                          const float* __restrict__ a_dst, float* __restrict__ als,
                          float* __restrict__ ald, int NH) {
    int i = blockIdx.x * blockDim.x + threadIdx.x;
    if (i >= NH) return;
    int h = i & 15;
    const float4* hp = (const float4*)(H + (size_t)i * 16);
    const float4* as = (const float4*)(a_src + h * 16);
    const float4* ad = (const float4*)(a_dst + h * 16);
    float s = 0.f, d = 0.f;
#pragma unroll
    for (int q = 0; q < 4; ++q) {
        float4 hv = hp[q], sv = as[q], dv = ad[q];
        s += hv.x * sv.x + hv.y * sv.y + hv.z * sv.z + hv.w * sv.w;
        d += hv.x * dv.x + hv.y * dv.y + hv.z * dv.z + hv.w * dv.w;
    }
    als[i] = s;
    ald[i] = d;
}

// ---------- layer-2 attention logits: wave per node, D=256 ----------
__global__ __launch_bounds__(256) void k_logits2(const float* __restrict__ H,
                                                 const float* __restrict__ a_src,
                                                 const float* __restrict__ a_dst,
                                                 float* __restrict__ als,
                                                 float* __restrict__ ald, int N) {
    int wave = threadIdx.x >> 6, lane = threadIdx.x & 63;
    int n = blockIdx.x * 4 + wave;
    if (n >= N) return;
    float4 hv = *(const float4*)(H + (size_t)n * 256 + lane * 4);
    float4 sv = *(const float4*)(a_src + lane * 4);
    float4 dv = *(const float4*)(a_dst + lane * 4);
    float s = hv.x * sv.x + hv.y * sv.y + hv.z * sv.z + hv.w * sv.w;
    float d = hv.x * dv.x + hv.y * dv.y + hv.z * dv.z + hv.w * dv.w;
#pragma unroll
    for (int off = 32; off >= 1; off >>= 1) {
        s += __shfl_xor(s, off);
        d += __shfl_xor(d, off);
    }
    if (lane == 0) { als[n] = s; ald[n] = d; }
}

// ---------- XCD-pinned GAT gather, 1 head, 4 groups x 64 channels ----------
// cg = blockIdx.x & 3 -> XCDs {cg, cg+4}; per-XCD H footprint 2.5MB (L2-fits).
// Wave per node; lane owns float2 (8B); half-wave per edge (2 edges/instr).
// Edge loop: unpredicated full 64-chunks + guarded tail.
__global__ __launch_bounds__(256) void k_gather_h1(
    const int* __restrict__ rowptr, const int* __restrict__ col,
    const float* __restrict__ H, const float* __restrict__ als,
    const float* __restrict__ ald, const float* __restrict__ bias,
    float* __restrict__ out, int N) {
    __shared__ float2 sw[4][64];
    int wave = threadIdx.x >> 6, lane = threadIdx.x & 63;
    int b = blockIdx.x;
    int cg = b & 3;
    int n = (b >> 2) * 4 + wave;
    if (n >= N) return;
    int c31 = lane & 31;
    int ep = lane >> 5;
    int start = rowptr[n], end = rowptr[n + 1];
    float aldv = ald[n];
    float2 acc = {0.f, 0.f};
    float swsum = 0.f;
    const float* Hc = H + cg * 64 + c31 * 2;
    int base = start;
    for (; base + 64 <= end; base += 64) {
        int s = col[base + lane];
        float v = als[s] + aldv;
        v = v >= 0.f ? v : NEG_SLOPE * v;
        float w = __expf(v);
        swsum += w;
        sw[wave][lane] = make_float2(__int_as_float(s), w);
        LDS_FENCE();
#pragma unroll 8
        for (int e = 0; e < 64; e += 2) {
            float2 p = sw[wave][e + ep];
            float2 hv = *(const float2*)(Hc + (size_t)__float_as_int(p.x) * 256);
            acc.x = fmaf(p.y, hv.x, acc.x);
            acc.y = fmaf(p.y, hv.y, acc.y);
        }
        LDS_FENCE();
    }
    int len = end - base;
    if (len > 0) {
        int s = 0;
        float w = 0.f;
        if (lane < len) {
            s = col[base + lane];
            float v = als[s] + aldv;
            v = v >= 0.f ? v : NEG_SLOPE * v;
            w = __expf(v);
        }
        swsum += w;
        sw[wave][lane] = make_float2(__int_as_float(s), w);
        LDS_FENCE();
        for (int e = 0; e < len; e += 2) {
            int eb = e + ep;
            if (eb < len) {
                float2 p = sw[wave][eb];
                float2 hv = *(const float2*)(Hc + (size_t)__float_as_int(p.x) * 256);
                acc.x = fmaf(p.y, hv.x, acc.x);
                acc.y = fmaf(p.y, hv.y, acc.y);
            }
        }
        LDS_FENCE();
    }
#pragma unroll
    for (int off = 32; off >= 1; off >>= 1) swsum += __shfl_xor(swsum, off);
    float inv = 1.0f / swsum;
    acc.x += __shfl_xor(acc.x, 32);   // combine even/odd edge partials
    acc.y += __shfl_xor(acc.y, 32);
    if (lane < 32) {
        int ch = cg * 64 + c31 * 2;
        float2 r;
        r.x = fmaf(acc.x, inv, bias[ch]);
        r.y = fmaf(acc.y, inv, bias[ch + 1]);
        *(float2*)(out + (size_t)n * 256 + ch) = r;
    }
}

// ---------- XCD-pinned GAT gather, 16 heads x 16ch, 4 groups x 64 channels ----------
// Group cg covers heads cg*4..cg*4+3. Staging per 32-edge chunk: 2 rounds,
// lane computes w for (edge lane&31, head cg*4 + ep + 2r) -> no redundancy
// across groups. w_lds stride 5 (coprime 32) -> conflict-free.
__global__ __launch_bounds__(256) void k_gather_h16(
    const int* __restrict__ rowptr, const int* __restrict__ col,
    const float* __restrict__ H, const float* __restrict__ als,
    const float* __restrict__ ald, const float* __restrict__ bias,
    float* __restrict__ out, int N) {
    __shared__ int s_lds[4][32];
    __shared__ float w_lds[4][32 * 5];   // [edge*5 + head-in-group]
    int wave = threadIdx.x >> 6, lane = threadIdx.x & 63;
    int b = blockIdx.x;
    int cg = b & 3;
    int n = (b >> 2) * 4 + wave;
    if (n >= N) return;
    int c31 = lane & 31;
    int ep = lane >> 5;
    int hl = c31 >> 3;                   // head-in-group of this lane's channels
    int eS = c31;                        // staging edge slot
    int hS0 = (cg << 2) + ep;            // staged heads: round 0
    int hS1 = hS0 + 2;                   //               round 1
    int start = rowptr[n], end = rowptr[n + 1];
    float ald0 = ald[n * 16 + hS0];
    float ald1 = ald[n * 16 + hS1];
    float2 acc = {0.f, 0.f};
    float swp0 = 0.f, swp1 = 0.f;
    const float* Hc = H + cg * 64 + c31 * 2;
    int base = start;
    for (; base + 32 <= end; base += 32) {
        if (lane < 32) s_lds[wave][lane] = col[base + lane];
        LDS_FENCE();
        {
            int s = s_lds[wave][eS];
            float v0 = als[s * 16 + hS0] + ald0;
            v0 = v0 >= 0.f ? v0 : NEG_SLOPE * v0;
            float w0 = __expf(v0);
            w_lds[wave][eS * 5 + ep] = w0;
            swp0 += w0;
            float v1 = als[s * 16 + hS1] + ald1;
            v1 = v1 >= 0.f ? v1 : NEG_SLOPE * v1;
            float w1 = __expf(v1);
            w_lds[wave][eS * 5 + ep + 2] = w1;
            swp1 += w1;
        }
        LDS_FENCE();
#pragma unroll 8
        for (int e = 0; e < 32; e += 2) {
            int eb = e + ep;
            int s = s_lds[wave][eb];
            float wv = w_lds[wave][eb * 5 + hl];
            float2 hv = *(const float2*)(Hc + (size_t)s * 256);
            acc.x = fmaf(wv, hv.x, acc.x);
            acc.y = fmaf(wv, hv.y, acc.y);
        }
        LDS_FENCE();
    }
    int len = end - base;
    if (len > 0) {
        if (lane < 32) s_lds[wave][lane] = (lane < len) ? col[base + lane] : 0;
        LDS_FENCE();
        {
            float w0 = 0.f, w1 = 0.f;
            if (eS < len) {
                int s = s_lds[wave][eS];
                float v0 = als[s * 16 + hS0] + ald0;
                v0 = v0 >= 0.f ? v0 : NEG_SLOPE * v0;
                w0 = __expf(v0);
                float v1 = als[s * 16 + hS1] + ald1;
                v1 = v1 >= 0.f ? v1 : NEG_SLOPE * v1;
                w1 = __expf(v1);
            }
            w_lds[wave][eS * 5 + ep] = w0;
            w_lds[wave][eS * 5 + ep + 2] = w1;
            swp0 += w0;
            swp1 += w1;
        }
        LDS_FENCE();
        for (int e = 0; e < len; e += 2) {
            int eb = e + ep;
            if (eb < len) {
                int s = s_lds[wave][eb];
                float wv = w_lds[wave][eb * 5 + hl];
                float2 hv = *(const float2*)(Hc + (size_t)s * 256);
                acc.x = fmaf(wv, hv.x, acc.x);
                acc.y = fmaf(wv, hv.y, acc.y);
            }
        }
        LDS_FENCE();
    }
    // head sums: swp0 -> heads cg*4+{0,1} (lanes<32 / >=32), swp1 -> +{2,3}
#pragma unroll
    for (int off = 1; off < 32; off <<= 1) {
        swp0 += __shfl_xor(swp0, off);
        swp1 += __shfl_xor(swp1, off);
    }
    float h0 = __shfl(swp0, 0), h1v = __shfl(swp0, 32);
    float h2 = __shfl(swp1, 0), h3 = __shfl(swp1, 32);
    float hs = (hl == 0) ? h0 : (hl == 1) ? h1v : (hl == 2) ? h2 : h3;
    float inv = 1.0f / hs;
    acc.x += __shfl_xor(acc.x, 32);
    acc.y += __shfl_xor(acc.y, 32);
    if (lane < 32) {
        int ch = cg * 64 + c31 * 2;
        float2 r;
        r.x = fmaxf(fmaf(acc.x, inv, bias[ch]), 0.f);
        r.y = fmaxf(fmaf(acc.y, inv, bias[ch + 1]), 0.f);
        *(float2*)(out + (size_t)n * 256 + ch) = r;
    }
}

// ---------- fused mean-pool + final linear: one block per graph ----------
__device__ __forceinline__ int lower_bound_i(const int* __restrict__ a, int n, int v) {
    int lo = 0, hi = n;
    while (lo < hi) {
        int mid = (lo + hi) >> 1;
        if (a[mid] < v) lo = mid + 1; else hi = mid;
    }
    return lo;
}

__global__ __launch_bounds__(1024) void k_pool_final(const float* __restrict__ B,
                                                     const int* __restrict__ batch,
                                                     const float* __restrict__ lw,
                                                     const float* __restrict__ lb,
                                                     float* __restrict__ out,
                                                     int N, int L) {
    __shared__ float psum[4][256];
    __shared__ float csum[256];
    int t = threadIdx.x;
    int c = t & 255, q = t >> 8;
    int g = blockIdx.x;
    int lo = lower_bound_i(batch, N, g);
    int hi = lower_bound_i(batch, N, g + 1);
    int len = hi - lo;
    int per = (len + 3) >> 2;
    int s0 = lo + q * per, s1 = min(hi, s0 + per);
    float acc = 0.f;
    for (int r = s0; r < s1; ++r) acc += B[(size_t)r * 256 + c];
    psum[q][c] = acc;
    __syncthreads();
    if (t < 256) csum[t] = psum[0][t] + psum[1][t] + psum[2][t] + psum[3][t];
    __syncthreads();
    int wave = t >> 6, lane = t & 63;
    if (wave < L) {
        int l = wave;
        float a = csum[lane] * lw[lane * L + l] +
                  csum[lane + 64] * lw[(lane + 64) * L + l] +
                  csum[lane + 128] * lw[(lane + 128) * L + l] +
                  csum[lane + 192] * lw[(lane + 192) * L + l];
#pragma unroll
        for (int off = 32; off >= 1; off >>= 1) a += __shfl_xor(a, off);
        if (lane == 0) out[g * L + l] = a / fmaxf((float)len, 1.0f) + lb[l];
    }
}

extern "C" void kernel_launch(void* const* d_in, const int* in_sizes, int n_in,
                              void* d_out, int out_size, void* d_ws, size_t ws_size,
                              hipStream_t stream) {
    const float* x   = (const float*)d_in[0];
    const int*   ei  = (const int*)d_in[1];
    const int*   bat = (const int*)d_in[2];
    const float* W1  = (const float*)d_in[3];
    const float* as1 = (const float*)d_in[4];
    const float* ad1 = (const float*)d_in[5];
    const float* b1  = (const float*)d_in[6];
    const float* W2  = (const float*)d_in[7];
    const float* as2 = (const float*)d_in[8];
    const float* ad2 = (const float*)d_in[9];
    const float* b2  = (const float*)d_in[10];
    const float* lw  = (const float*)d_in[11];
    const float* lb  = (const float*)d_in[12];
    float* out = (float*)d_out;

    const int N = in_sizes[2];        // 10000
    const int E = in_sizes[1] / 2;    // 320000
    const int G = 64, L = 10;
    const int Etot = E + N;
    const int NP = (N + 31) >> 5;     // partitions of 32 dsts (313)
    const int CE = (Etot + CSR_NB - 1) / CSR_NB;

    // workspace layout
    float* A    = (float*)d_ws;              // [N,256] h1 then h2
    float* B    = A + (size_t)N * 256;       // [N,256] out1 then out2
    float* als1 = B + (size_t)N * 256;       // [N,16]
    float* ald1 = als1 + (size_t)N * 16;
    float* als2 = ald1 + (size_t)N * 16;     // [N]
    float* ald2 = als2 + N;
    int* rowptr   = (int*)(ald2 + N);        // [N+1]
    int* col      = rowptr + N + 1;          // [Etot]
    int* tmp      = col + Etot;              // [Etot] packed (src<<5)|d5
    int* hist     = tmp + Etot;              // [NP*CSR_NB] transposed
    int* partBase = hist + NP * CSR_NB;      // [NP+1]
    int* partTot  = partBase + NP + 1;       // [NP]

    const int BS = 256;
    auto nb = [](int n, int b) { return (n + b - 1) / b; };
    int nodes4 = nb(N, 4);
    int rows32 = nb(N, 32);

    // ---- CSR build: partition sort, parallel scan, no global returning atomics ----
    k_parthist<<<CSR_NB, BS, 0, stream>>>(ei, E, N, NP, CE, hist);
    k_partreduce<<<NP, 128, 0, stream>>>(hist, partTot);
    k_partbase<<<1, 512, 0, stream>>>(partTot, NP, partBase, rowptr, N);
    k_partscatter<<<CSR_NB, BS, 0, stream>>>(ei, E, N, NP, CE, hist, partBase, tmp);
    k_csr_final<<<NP, BS, 0, stream>>>(tmp, partBase, rowptr, col, N);

    // ---- layer 1 ----
    k_gemm_cs<128><<<dim3(rows32, 2), BS, 0, stream>>>(x, W1, A, N);
    k_logits1<<<nb(N * 16, BS), BS, 0, stream>>>(A, as1, ad1, als1, ald1, N * 16);
    k_gather_h16<<<4 * nodes4, BS, 0, stream>>>(rowptr, col, A, als1, ald1, b1, B, N);

    // ---- layer 2 ----
    k_gemm_cs<256><<<dim3(rows32, 2), BS, 0, stream>>>(B, W2, A, N);
    k_logits2<<<nodes4, BS, 0, stream>>>(A, as2, ad2, als2, ald2, N);
    k_gather_h1<<<4 * nodes4, BS, 0, stream>>>(rowptr, col, A, als2, ald2, b2, B, N);

    // ---- fused pool + final linear ----
    k_pool_final<<<G, 1024, 0, stream>>>(B, bat, lw, lb, out, N, L);
}